// Round 1
// baseline (682.901 us; speedup 1.0000x reference)
//
#include <hip/hip_runtime.h>
#include <cstddef>

#define NPIX 4096
#define CDIM 512

// -------------------------------------------------------------------------
// Kernel 1: P[b, 0:384, n] = concat(wA,wB,wC) @ x[b]   (fp32 SGEMM)
// grid (32 n-tiles, 3 m-tiles, 16 batches), block 256, BM=BN=128, BK=16
// -------------------------------------------------------------------------
__global__ __launch_bounds__(256)
void conv_gemm(const float* __restrict__ x, const float* __restrict__ wA,
               const float* __restrict__ wB, const float* __restrict__ wC,
               float* __restrict__ P)
{
    const int b  = blockIdx.z;
    const int mt = blockIdx.y;
    const int nt = blockIdx.x;
    const float* __restrict__ W = (mt == 0) ? wA : (mt == 1) ? wB : wC; // [128,512]
    const float* __restrict__ X = x + (size_t)b * CDIM * NPIX + nt * 128;

    __shared__ float As[16][132];   // [k][m], +4 pad
    __shared__ float Bs[16][132];   // [k][n], +4 pad

    const int tid = threadIdx.x;
    const int tr  = tid >> 4;   // 0..15
    const int tc  = tid & 15;   // 0..15

    float acc[8][8];
#pragma unroll
    for (int i = 0; i < 8; ++i)
#pragma unroll
        for (int j = 0; j < 8; ++j) acc[i][j] = 0.f;

    for (int kt = 0; kt < CDIM; kt += 16) {
#pragma unroll
        for (int l = 0; l < 2; ++l) {             // A tile: 128 rows x 16 k, transposed
            int idx = tid + l * 256;
            int m   = idx >> 2;
            int k4  = (idx & 3) << 2;
            float4 v = *(const float4*)(W + m * CDIM + kt + k4);
            As[k4 + 0][m] = v.x;
            As[k4 + 1][m] = v.y;
            As[k4 + 2][m] = v.z;
            As[k4 + 3][m] = v.w;
        }
#pragma unroll
        for (int l = 0; l < 2; ++l) {             // B tile: 16 k x 128 n, direct
            int idx = tid + l * 256;
            int k   = idx >> 5;
            int n4  = (idx & 31) << 2;
            *(float4*)(&Bs[k][n4]) = *(const float4*)(X + (size_t)(kt + k) * NPIX + n4);
        }
        __syncthreads();
#pragma unroll
        for (int kk = 0; kk < 16; ++kk) {
            float a[8], bb[8];
            *(float4*)(&a[0])  = *(const float4*)(&As[kk][tr * 8]);
            *(float4*)(&a[4])  = *(const float4*)(&As[kk][tr * 8 + 4]);
            *(float4*)(&bb[0]) = *(const float4*)(&Bs[kk][tc * 8]);
            *(float4*)(&bb[4]) = *(const float4*)(&Bs[kk][tc * 8 + 4]);
#pragma unroll
            for (int i = 0; i < 8; ++i)
#pragma unroll
                for (int j = 0; j < 8; ++j) acc[i][j] = fmaf(a[i], bb[j], acc[i][j]);
        }
        __syncthreads();
    }

    float* Pb = P + ((size_t)b * 384 + mt * 128) * NPIX + nt * 128;
#pragma unroll
    for (int i = 0; i < 8; ++i) {
        float* row = Pb + (size_t)(tr * 8 + i) * NPIX + tc * 8;
        *(float4*)(row)     = *(float4*)(&acc[i][0]);
        *(float4*)(row + 4) = *(float4*)(&acc[i][4]);
    }
}

// -------------------------------------------------------------------------
// Kernel 2: row softmax over N=4096, in place, on A rows (0..127) and
// Cs rows (256..383) of P. One block per row; 256 thr x 16 elems.
// -------------------------------------------------------------------------
__global__ __launch_bounds__(256)
void softmax_rows(float* __restrict__ P)
{
    const int blk = blockIdx.x;            // 0..4095
    const int b   = blk >> 8;
    const int r   = blk & 255;
    const int m   = (r < 128) ? r : (r + 128);
    float* row = P + ((size_t)b * 384 + m) * NPIX;
    const int tid = threadIdx.x;

    float4 v[4];
    float mx = -3.402823466e38f;
#pragma unroll
    for (int j = 0; j < 4; ++j) {
        v[j] = *(const float4*)(row + j * 1024 + tid * 4);
        mx = fmaxf(mx, fmaxf(fmaxf(v[j].x, v[j].y), fmaxf(v[j].z, v[j].w)));
    }
#pragma unroll
    for (int o = 32; o > 0; o >>= 1) mx = fmaxf(mx, __shfl_xor(mx, o));
    __shared__ float redm[4];
    __shared__ float reds[4];
    const int wid = tid >> 6, lane = tid & 63;
    if (lane == 0) redm[wid] = mx;
    __syncthreads();
    mx = fmaxf(fmaxf(redm[0], redm[1]), fmaxf(redm[2], redm[3]));

    float s = 0.f;
#pragma unroll
    for (int j = 0; j < 4; ++j) {
        v[j].x = __expf(v[j].x - mx);
        v[j].y = __expf(v[j].y - mx);
        v[j].z = __expf(v[j].z - mx);
        v[j].w = __expf(v[j].w - mx);
        s += (v[j].x + v[j].y) + (v[j].z + v[j].w);
    }
#pragma unroll
    for (int o = 32; o > 0; o >>= 1) s += __shfl_xor(s, o);
    if (lane == 0) reds[wid] = s;
    __syncthreads();
    s = (reds[0] + reds[1]) + (reds[2] + reds[3]);
    const float inv = 1.f / s;
#pragma unroll
    for (int j = 0; j < 4; ++j) {
        v[j].x *= inv; v[j].y *= inv; v[j].z *= inv; v[j].w *= inv;
        *(float4*)(row + j * 1024 + tid * 4) = v[j];
    }
}

// -------------------------------------------------------------------------
// Kernel 3: G partials. Gp[b][kc] = Bf[:, kc-chunk] @ A[:, kc-chunk]^T
// grid (16 k-chunks of 256, 16 batches); 128x128 output tile per block.
// -------------------------------------------------------------------------
__global__ __launch_bounds__(256)
void g_partial(const float* __restrict__ P, float* __restrict__ Gp)
{
    const int kc = blockIdx.x;    // 0..15
    const int b  = blockIdx.y;
    const float* __restrict__ Arow = P + (size_t)b * 384 * NPIX;   // softmaxed A
    const float* __restrict__ Brow = Arow + (size_t)128 * NPIX;    // Bf

    __shared__ float Hs[16][132];  // [k][h] from Bf
    __shared__ float Gs[16][132];  // [k][g] from A

    const int tid = threadIdx.x;
    const int tr  = tid >> 4;
    const int tc  = tid & 15;

    float acc[8][8];
#pragma unroll
    for (int i = 0; i < 8; ++i)
#pragma unroll
        for (int j = 0; j < 8; ++j) acc[i][j] = 0.f;

    for (int kt = 0; kt < 256; kt += 16) {
        const int nb = kc * 256 + kt;
#pragma unroll
        for (int l = 0; l < 2; ++l) {
            int idx = tid + l * 256;
            int rr  = idx >> 2;
            int k4  = (idx & 3) << 2;
            float4 v = *(const float4*)(Brow + (size_t)rr * NPIX + nb + k4);
            Hs[k4 + 0][rr] = v.x; Hs[k4 + 1][rr] = v.y;
            Hs[k4 + 2][rr] = v.z; Hs[k4 + 3][rr] = v.w;
            float4 u = *(const float4*)(Arow + (size_t)rr * NPIX + nb + k4);
            Gs[k4 + 0][rr] = u.x; Gs[k4 + 1][rr] = u.y;
            Gs[k4 + 2][rr] = u.z; Gs[k4 + 3][rr] = u.w;
        }
        __syncthreads();
#pragma unroll
        for (int kk = 0; kk < 16; ++kk) {
            float h8[8], g8[8];
            *(float4*)(&h8[0]) = *(const float4*)(&Hs[kk][tr * 8]);
            *(float4*)(&h8[4]) = *(const float4*)(&Hs[kk][tr * 8 + 4]);
            *(float4*)(&g8[0]) = *(const float4*)(&Gs[kk][tc * 8]);
            *(float4*)(&g8[4]) = *(const float4*)(&Gs[kk][tc * 8 + 4]);
#pragma unroll
            for (int i = 0; i < 8; ++i)
#pragma unroll
                for (int j = 0; j < 8; ++j) acc[i][j] = fmaf(h8[i], g8[j], acc[i][j]);
        }
        __syncthreads();
    }

    float* O = Gp + ((size_t)b * 16 + kc) * 16384;
#pragma unroll
    for (int i = 0; i < 8; ++i) {
        float* row = O + (size_t)(tr * 8 + i) * 128 + tc * 8;
        *(float4*)(row)     = *(float4*)(&acc[i][0]);
        *(float4*)(row + 4) = *(float4*)(&acc[i][4]);
    }
}

// -------------------------------------------------------------------------
// Kernel 4a: G = sum over 16 partials. grid 256, 4 floats/thread.
// -------------------------------------------------------------------------
__global__ __launch_bounds__(256)
void g_reduce(const float* __restrict__ Gp, float* __restrict__ G)
{
    const int t    = blockIdx.x * 256 + threadIdx.x;  // 0..65535
    const int flat = t * 4;
    const int b    = flat >> 14;
    const int rr   = flat & 16383;
    const float* base = Gp + (size_t)b * 16 * 16384 + rr;
    float4 s = make_float4(0.f, 0.f, 0.f, 0.f);
#pragma unroll
    for (int kc = 0; kc < 16; ++kc) {
        float4 v = *(const float4*)(base + (size_t)kc * 16384);
        s.x += v.x; s.y += v.y; s.z += v.z; s.w += v.w;
    }
    *(float4*)(G + (size_t)b * 16384 + rr) = s;
}

// -------------------------------------------------------------------------
// Kernel 4b: M[b] = wProj @ G[b]   ([512,128]@[128,128])
// grid (16 c-tiles of 32, 16 batches); G[b] staged in LDS.
// -------------------------------------------------------------------------
__global__ __launch_bounds__(256)
void proj_g(const float* __restrict__ G, const float* __restrict__ wProj,
            float* __restrict__ M)
{
    const int ct = blockIdx.x;  // 0..15
    const int b  = blockIdx.y;
    __shared__ float Gs[16384]; // [h][g]
    const int tid = threadIdx.x;
    const float* Gb = G + (size_t)b * 16384;
#pragma unroll
    for (int l = 0; l < 16; ++l) {
        int i4 = (tid + l * 256) * 4;
        *(float4*)(&Gs[i4]) = *(const float4*)(Gb + i4);
    }
    __syncthreads();
    const int g  = tid & 127;
    const int cl = tid >> 7;        // 0/1
    const int c0 = ct * 32 + cl;
    float acc[16];
#pragma unroll
    for (int i = 0; i < 16; ++i) acc[i] = 0.f;
    for (int h = 0; h < 128; ++h) {
        const float gv = Gs[h * 128 + g];
#pragma unroll
        for (int cc = 0; cc < 16; ++cc)
            acc[cc] = fmaf(wProj[(size_t)(c0 + cc * 2) * 128 + h], gv, acc[cc]);
    }
    float* Mb = M + (size_t)b * 512 * 128;
#pragma unroll
    for (int cc = 0; cc < 16; ++cc)
        Mb[(size_t)(c0 + cc * 2) * 128 + g] = acc[cc];
}

// -------------------------------------------------------------------------
// Kernel 5: out[b,c,n] = s_c * (M[b] @ Cs[b])[c,n] + t_c   (fused BN)
// grid (32 n-tiles, 8 c-tiles of 64, 16 batches); BM=64, BN=128, BK=32.
// -------------------------------------------------------------------------
__global__ __launch_bounds__(256)
void final_gemm(const float* __restrict__ P, const float* __restrict__ Mw,
                const float* __restrict__ gamma, const float* __restrict__ beta,
                const float* __restrict__ mean,  const float* __restrict__ var,
                float* __restrict__ out)
{
    const int nt = blockIdx.x;
    const int ct = blockIdx.y;
    const int b  = blockIdx.z;
    const float* __restrict__ Cs = P + ((size_t)b * 384 + 256) * NPIX + nt * 128;
    const float* __restrict__ Mb = Mw + ((size_t)b * 512 + ct * 64) * 128;

    __shared__ float Ms[32][68];    // [g][c], +4 pad
    __shared__ float Ns[32][132];   // [g][n], +4 pad

    const int tid = threadIdx.x;
    const int tr  = tid >> 4;   // 0..15 -> c
    const int tc  = tid & 15;   // 0..15 -> n

    float acc[4][8];
#pragma unroll
    for (int i = 0; i < 4; ++i)
#pragma unroll
        for (int j = 0; j < 8; ++j) acc[i][j] = 0.f;

    for (int kt = 0; kt < 128; kt += 32) {
#pragma unroll
        for (int l = 0; l < 2; ++l) {             // M tile 64c x 32g, transposed
            int idx = tid + l * 256;
            int c   = idx >> 3;
            int g4  = (idx & 7) << 2;
            float4 v = *(const float4*)(Mb + (size_t)c * 128 + kt + g4);
            Ms[g4 + 0][c] = v.x; Ms[g4 + 1][c] = v.y;
            Ms[g4 + 2][c] = v.z; Ms[g4 + 3][c] = v.w;
        }
#pragma unroll
        for (int l = 0; l < 4; ++l) {             // Cs tile 32g x 128n, direct
            int idx = tid + l * 256;
            int g   = idx >> 5;
            int n4  = (idx & 31) << 2;
            *(float4*)(&Ns[g][n4]) = *(const float4*)(Cs + (size_t)(kt + g) * NPIX + n4);
        }
        __syncthreads();
#pragma unroll
        for (int g = 0; g < 32; ++g) {
            float a[4], bb[8];
            *(float4*)(&a[0])  = *(const float4*)(&Ms[g][tr * 4]);
            *(float4*)(&bb[0]) = *(const float4*)(&Ns[g][tc * 8]);
            *(float4*)(&bb[4]) = *(const float4*)(&Ns[g][tc * 8 + 4]);
#pragma unroll
            for (int i = 0; i < 4; ++i)
#pragma unroll
                for (int j = 0; j < 8; ++j) acc[i][j] = fmaf(a[i], bb[j], acc[i][j]);
        }
        __syncthreads();
    }

    const int n0 = nt * 128 + tc * 8;
    float* ob = out + (size_t)b * CDIM * NPIX;
#pragma unroll
    for (int i = 0; i < 4; ++i) {
        const int c = ct * 64 + tr * 4 + i;
        const float s = gamma[c] / sqrtf(var[c] + 1e-5f);
        const float t = beta[c] - mean[c] * s;
        float4 o0, o1;
        o0.x = fmaf(acc[i][0], s, t); o0.y = fmaf(acc[i][1], s, t);
        o0.z = fmaf(acc[i][2], s, t); o0.w = fmaf(acc[i][3], s, t);
        o1.x = fmaf(acc[i][4], s, t); o1.y = fmaf(acc[i][5], s, t);
        o1.z = fmaf(acc[i][6], s, t); o1.w = fmaf(acc[i][7], s, t);
        float* row = ob + (size_t)c * NPIX + n0;
        *(float4*)(row)     = o0;
        *(float4*)(row + 4) = o1;
    }
}

// -------------------------------------------------------------------------
extern "C" void kernel_launch(void* const* d_in, const int* in_sizes, int n_in,
                              void* d_out, int out_size, void* d_ws, size_t ws_size,
                              hipStream_t stream)
{
    const float* x     = (const float*)d_in[0];
    const float* wA    = (const float*)d_in[1];
    const float* wB    = (const float*)d_in[2];
    const float* wC    = (const float*)d_in[3];
    const float* wProj = (const float*)d_in[4];
    const float* gamma = (const float*)d_in[5];
    const float* beta  = (const float*)d_in[6];
    const float* mean  = (const float*)d_in[7];
    const float* var   = (const float*)d_in[8];
    float* out = (float*)d_out;

    char* ws = (char*)d_ws;
    float* P  = (float*)(ws);                                   // 16*384*4096*4   = 100663296
    float* Gp = (float*)(ws + 100663296);                       // 16*16*16384*4   =  16777216
    float* G  = (float*)(ws + 100663296 + 16777216);            // 16*16384*4      =   1048576
    float* M  = (float*)(ws + 100663296 + 16777216 + 1048576);  // 16*512*128*4    =   4194304
    // total ws use: 122683392 bytes

    conv_gemm   <<<dim3(32, 3, 16), 256, 0, stream>>>(x, wA, wB, wC, P);
    softmax_rows<<<dim3(4096),      256, 0, stream>>>(P);
    g_partial   <<<dim3(16, 16),    256, 0, stream>>>(P, Gp);
    g_reduce    <<<dim3(256),       256, 0, stream>>>(Gp, G);
    proj_g      <<<dim3(16, 16),    256, 0, stream>>>(G, wProj, M);
    final_gemm  <<<dim3(32, 8, 16), 256, 0, stream>>>(P, M, gamma, beta, mean, var, out);
}

// Round 2
// 386.100 us; speedup vs baseline: 1.7687x; 1.7687x over previous
//
#include <hip/hip_runtime.h>
#include <cstddef>

#define NPIX 4096
#define CDIM 512

typedef _Float16 half8 __attribute__((ext_vector_type(8)));
typedef float f32x4 __attribute__((ext_vector_type(4)));

__device__ __forceinline__ void gl_lds16(const void* g, void* l) {
    __builtin_amdgcn_global_load_lds(
        (const __attribute__((address_space(1))) void*)g,
        (__attribute__((address_space(3))) void*)l, 16, 0, 0);
}

// -------------------------------------------------------------------------
// prep_w: wA/wB/wC fp32 [128][512] -> frag-blocked fp16 Wh.
// frag_id = mt*128 + kt*8 + msub ; lane holds W[msub*16+(lane&15)][kt*32+(lane>>4)*8+j]
// -------------------------------------------------------------------------
__global__ __launch_bounds__(256)
void prep_w(const float* __restrict__ wA, const float* __restrict__ wB,
            const float* __restrict__ wC, _Float16* __restrict__ Wh)
{
    const int gid  = blockIdx.x * 256 + threadIdx.x;   // 0..24575
    const int lane = gid & 63;
    const int frag = gid >> 6;                         // 0..383
    const int msub = frag & 7, kt = (frag >> 3) & 15, mt = frag >> 7;
    const float* __restrict__ W = (mt == 0) ? wA : (mt == 1) ? wB : wC;
    const int m  = msub * 16 + (lane & 15);
    const int c0 = kt * 32 + ((lane >> 4) << 3);
    const float* src = W + m * CDIM + c0;
    union { _Float16 h[8]; float4 f; } u;
#pragma unroll
    for (int j = 0; j < 8; ++j) u.h[j] = (_Float16)src[j];
    *(float4*)(Wh + (size_t)frag * 512 + lane * 8) = u.f;
}

// -------------------------------------------------------------------------
// m_to_h: M fp32 [b][512][128] -> frag-blocked fp16 Mh for final_mfma A-op.
// frag_id = ((b*4+ct)*4+kt)*8 + msub
// lane holds M[b][ct*128+msub*16+(lane&15)][kt*32+(lane>>4)*8+j]
// -------------------------------------------------------------------------
__global__ __launch_bounds__(256)
void m_to_h(const float* __restrict__ M, _Float16* __restrict__ Mh)
{
    const int gid  = blockIdx.x * 256 + threadIdx.x;   // 0..131071
    const int lane = gid & 63;
    const int frag = gid >> 6;                         // 0..2047
    const int msub = frag & 7, kt = (frag >> 3) & 3, ct = (frag >> 5) & 3, b = frag >> 7;
    const float* src = M + ((size_t)b * 512 + ct * 128 + msub * 16 + (lane & 15)) * 128
                         + kt * 32 + ((lane >> 4) << 3);
    union { _Float16 h[8]; float4 f; } u;
#pragma unroll
    for (int j = 0; j < 8; ++j) u.h[j] = (_Float16)src[j];
    *(float4*)(Mh + (size_t)frag * 512 + lane * 8) = u.f;
}

// -------------------------------------------------------------------------
// conv_mfma: P[b, mt*128:+128, n] = W_mt @ x[b]  via fp16 MFMA 16x16x32.
// 128x128 tile, BK=32, 16 k-iters. A from Wh (global_load_lds), B fused
// fp32->fp16 transposed staging into swizzled [n][40] LDS.
// -------------------------------------------------------------------------
__global__ __launch_bounds__(256)
void conv_mfma(const float* __restrict__ x, const _Float16* __restrict__ Wh,
               float* __restrict__ P)
{
    const int nt = blockIdx.x, mt = blockIdx.y, b = blockIdx.z;
    const int tid  = threadIdx.x;
    const int wave = tid >> 6, lane = tid & 63;
    const int wm = wave >> 1, wn = wave & 1;

    __shared__ alignas(16) _Float16 sA[4096];        // 8 frag-blocks x 512
    __shared__ alignas(16) _Float16 sB[128 * 40];    // [n][32k + 8 pad], swizzled

    f32x4 acc[4][4];
#pragma unroll
    for (int i = 0; i < 4; ++i)
#pragma unroll
        for (int j = 0; j < 4; ++j)
#pragma unroll
            for (int e = 0; e < 4; ++e) acc[i][j][e] = 0.f;

    const int n0 = (tid & 31) << 2;        // 4 n-cols per thread
    const int k0 = (tid >> 5) << 2;        // 4 k-rows per thread (one k4-block)
    const float* xb = x + ((size_t)b << 21) + (nt << 7) + n0;
    const _Float16* WhB = Wh + (size_t)mt * 128 * 512;

    for (int kt = 0; kt < 16; ++kt) {
        // ---- stage A (weights) via global_load_lds, 2 frag-blocks per wave
#pragma unroll
        for (int s = 0; s < 2; ++s) {
            const int frag = wave + (s << 2);
            gl_lds16(WhB + ((size_t)kt * 8 + frag) * 512 + lane * 8, &sA[frag * 512]);
        }
        // ---- stage B (x) : read 4 float4, cvt fp16, transposed swizzled write
        const float* xs = xb + (size_t)(kt * 32 + k0) * NPIX;
        float ld[4][4];
        *(float4*)&ld[0][0] = *(const float4*)(xs);
        *(float4*)&ld[1][0] = *(const float4*)(xs + NPIX);
        *(float4*)&ld[2][0] = *(const float4*)(xs + 2 * NPIX);
        *(float4*)&ld[3][0] = *(const float4*)(xs + 3 * NPIX);
#pragma unroll
        for (int c = 0; c < 4; ++c) {
            const int n    = n0 + c;
            const int blkh = ((k0 >> 2) ^ (((n >> 4) & 3) << 1)) << 2;
            union { _Float16 h[4]; float2 f; } u;
            u.h[0] = (_Float16)ld[0][c];
            u.h[1] = (_Float16)ld[1][c];
            u.h[2] = (_Float16)ld[2][c];
            u.h[3] = (_Float16)ld[3][c];
            *(float2*)&sB[n * 40 + blkh] = u.f;
        }
        __syncthreads();

        half8 av[4], bv[4];
#pragma unroll
        for (int i = 0; i < 4; ++i)
            av[i] = *(const half8*)&sA[(((wm << 2) + i) << 9) + (lane << 3)];
#pragma unroll
        for (int j = 0; j < 4; ++j) {
            const int nj = (wn << 6) + (j << 4) + (lane & 15);
            const int qs = ((lane >> 4) ^ ((nj >> 4) & 3)) << 3;
            bv[j] = *(const half8*)&sB[nj * 40 + qs];
        }
#pragma unroll
        for (int i = 0; i < 4; ++i)
#pragma unroll
            for (int j = 0; j < 4; ++j)
                acc[i][j] = __builtin_amdgcn_mfma_f32_16x16x32_f16(av[i], bv[j], acc[i][j], 0, 0, 0);
        __syncthreads();
    }

    // ---- epilogue: D col = lane&15, row = (lane>>4)*4 + r  [m89/m91 layout]
    float* Pb = P + (((size_t)b * 384 + mt * 128) << 12) + (nt << 7);
#pragma unroll
    for (int i = 0; i < 4; ++i) {
        const int row0 = (wm << 6) + (i << 4) + ((lane >> 4) << 2);
#pragma unroll
        for (int j = 0; j < 4; ++j) {
            const int col = (wn << 6) + (j << 4) + (lane & 15);
#pragma unroll
            for (int r = 0; r < 4; ++r)
                Pb[(size_t)(row0 + r) * NPIX + col] = acc[i][j][r];
        }
    }
}

// -------------------------------------------------------------------------
// Kernel 2: row softmax over N=4096, in place (unchanged from R0).
// -------------------------------------------------------------------------
__global__ __launch_bounds__(256)
void softmax_rows(float* __restrict__ P)
{
    const int blk = blockIdx.x;
    const int b   = blk >> 8;
    const int r   = blk & 255;
    const int m   = (r < 128) ? r : (r + 128);
    float* row = P + ((size_t)b * 384 + m) * NPIX;
    const int tid = threadIdx.x;

    float4 v[4];
    float mx = -3.402823466e38f;
#pragma unroll
    for (int j = 0; j < 4; ++j) {
        v[j] = *(const float4*)(row + j * 1024 + tid * 4);
        mx = fmaxf(mx, fmaxf(fmaxf(v[j].x, v[j].y), fmaxf(v[j].z, v[j].w)));
    }
#pragma unroll
    for (int o = 32; o > 0; o >>= 1) mx = fmaxf(mx, __shfl_xor(mx, o));
    __shared__ float redm[4];
    __shared__ float reds[4];
    const int wid = tid >> 6, lane = tid & 63;
    if (lane == 0) redm[wid] = mx;
    __syncthreads();
    mx = fmaxf(fmaxf(redm[0], redm[1]), fmaxf(redm[2], redm[3]));

    float s = 0.f;
#pragma unroll
    for (int j = 0; j < 4; ++j) {
        v[j].x = __expf(v[j].x - mx);
        v[j].y = __expf(v[j].y - mx);
        v[j].z = __expf(v[j].z - mx);
        v[j].w = __expf(v[j].w - mx);
        s += (v[j].x + v[j].y) + (v[j].z + v[j].w);
    }
#pragma unroll
    for (int o = 32; o > 0; o >>= 1) s += __shfl_xor(s, o);
    if (lane == 0) reds[wid] = s;
    __syncthreads();
    s = (reds[0] + reds[1]) + (reds[2] + reds[3]);
    const float inv = 1.f / s;
#pragma unroll
    for (int j = 0; j < 4; ++j) {
        v[j].x *= inv; v[j].y *= inv; v[j].z *= inv; v[j].w *= inv;
        *(float4*)(row + j * 1024 + tid * 4) = v[j];
    }
}

// -------------------------------------------------------------------------
// Kernel 3: G partials (unchanged fp32).
// -------------------------------------------------------------------------
__global__ __launch_bounds__(256)
void g_partial(const float* __restrict__ P, float* __restrict__ Gp)
{
    const int kc = blockIdx.x;
    const int b  = blockIdx.y;
    const float* __restrict__ Arow = P + (size_t)b * 384 * NPIX;
    const float* __restrict__ Brow = Arow + (size_t)128 * NPIX;

    __shared__ float Hs[16][132];
    __shared__ float Gs[16][132];

    const int tid = threadIdx.x;
    const int tr  = tid >> 4;
    const int tc  = tid & 15;

    float acc[8][8];
#pragma unroll
    for (int i = 0; i < 8; ++i)
#pragma unroll
        for (int j = 0; j < 8; ++j) acc[i][j] = 0.f;

    for (int kt = 0; kt < 256; kt += 16) {
        const int nb = kc * 256 + kt;
#pragma unroll
        for (int l = 0; l < 2; ++l) {
            int idx = tid + l * 256;
            int rr  = idx >> 2;
            int k4  = (idx & 3) << 2;
            float4 v = *(const float4*)(Brow + (size_t)rr * NPIX + nb + k4);
            Hs[k4 + 0][rr] = v.x; Hs[k4 + 1][rr] = v.y;
            Hs[k4 + 2][rr] = v.z; Hs[k4 + 3][rr] = v.w;
            float4 u = *(const float4*)(Arow + (size_t)rr * NPIX + nb + k4);
            Gs[k4 + 0][rr] = u.x; Gs[k4 + 1][rr] = u.y;
            Gs[k4 + 2][rr] = u.z; Gs[k4 + 3][rr] = u.w;
        }
        __syncthreads();
#pragma unroll
        for (int kk = 0; kk < 16; ++kk) {
            float h8[8], g8[8];
            *(float4*)(&h8[0]) = *(const float4*)(&Hs[kk][tr * 8]);
            *(float4*)(&h8[4]) = *(const float4*)(&Hs[kk][tr * 8 + 4]);
            *(float4*)(&g8[0]) = *(const float4*)(&Gs[kk][tc * 8]);
            *(float4*)(&g8[4]) = *(const float4*)(&Gs[kk][tc * 8 + 4]);
#pragma unroll
            for (int i = 0; i < 8; ++i)
#pragma unroll
                for (int j = 0; j < 8; ++j) acc[i][j] = fmaf(h8[i], g8[j], acc[i][j]);
        }
        __syncthreads();
    }

    float* O = Gp + ((size_t)b * 16 + kc) * 16384;
#pragma unroll
    for (int i = 0; i < 8; ++i) {
        float* row = O + (size_t)(tr * 8 + i) * 128 + tc * 8;
        *(float4*)(row)     = *(float4*)(&acc[i][0]);
        *(float4*)(row + 4) = *(float4*)(&acc[i][4]);
    }
}

// -------------------------------------------------------------------------
// Kernel 4a: G = sum of partials (unchanged).
// -------------------------------------------------------------------------
__global__ __launch_bounds__(256)
void g_reduce(const float* __restrict__ Gp, float* __restrict__ G)
{
    const int t    = blockIdx.x * 256 + threadIdx.x;
    const int flat = t * 4;
    const int b    = flat >> 14;
    const int rr   = flat & 16383;
    const float* base = Gp + (size_t)b * 16 * 16384 + rr;
    float4 s = make_float4(0.f, 0.f, 0.f, 0.f);
#pragma unroll
    for (int kc = 0; kc < 16; ++kc) {
        float4 v = *(const float4*)(base + (size_t)kc * 16384);
        s.x += v.x; s.y += v.y; s.z += v.z; s.w += v.w;
    }
    *(float4*)(G + (size_t)b * 16384 + rr) = s;
}

// -------------------------------------------------------------------------
// Kernel 4b: M[b] = wProj @ G[b] (unchanged fp32).
// -------------------------------------------------------------------------
__global__ __launch_bounds__(256)
void proj_g(const float* __restrict__ G, const float* __restrict__ wProj,
            float* __restrict__ M)
{
    const int ct = blockIdx.x;
    const int b  = blockIdx.y;
    __shared__ float Gs[16384];
    const int tid = threadIdx.x;
    const float* Gb = G + (size_t)b * 16384;
#pragma unroll
    for (int l = 0; l < 16; ++l) {
        int i4 = (tid + l * 256) * 4;
        *(float4*)(&Gs[i4]) = *(const float4*)(Gb + i4);
    }
    __syncthreads();
    const int g  = tid & 127;
    const int cl = tid >> 7;
    const int c0 = ct * 32 + cl;
    float acc[16];
#pragma unroll
    for (int i = 0; i < 16; ++i) acc[i] = 0.f;
    for (int h = 0; h < 128; ++h) {
        const float gv = Gs[h * 128 + g];
#pragma unroll
        for (int cc = 0; cc < 16; ++cc)
            acc[cc] = fmaf(wProj[(size_t)(c0 + cc * 2) * 128 + h], gv, acc[cc]);
    }
    float* Mb = M + (size_t)b * 512 * 128;
#pragma unroll
    for (int cc = 0; cc < 16; ++cc)
        Mb[(size_t)(c0 + cc * 2) * 128 + g] = acc[cc];
}

// -------------------------------------------------------------------------
// final_mfma: out[b,c,n] = BN(M[b] @ Cs[b]) via fp16 MFMA. 128x128 tile,
// K=128 (4 iters of BK=32). A from Mh (global_load_lds), B = Cs rows of P
// with fused fp32->fp16 transposed staging. BN fused in epilogue.
// -------------------------------------------------------------------------
__global__ __launch_bounds__(256)
void final_mfma(const float* __restrict__ P, const _Float16* __restrict__ Mh,
                const float* __restrict__ gamma, const float* __restrict__ beta,
                const float* __restrict__ mean,  const float* __restrict__ var,
                float* __restrict__ out)
{
    const int nt = blockIdx.x, ct = blockIdx.y, b = blockIdx.z;
    const int tid  = threadIdx.x;
    const int wave = tid >> 6, lane = tid & 63;
    const int wm = wave >> 1, wn = wave & 1;

    __shared__ alignas(16) _Float16 sA[4096];
    __shared__ alignas(16) _Float16 sB[128 * 40];

    f32x4 acc[4][4];
#pragma unroll
    for (int i = 0; i < 4; ++i)
#pragma unroll
        for (int j = 0; j < 4; ++j)
#pragma unroll
            for (int e = 0; e < 4; ++e) acc[i][j][e] = 0.f;

    const int n0 = (tid & 31) << 2;
    const int k0 = (tid >> 5) << 2;
    const float* Cs = P + (((size_t)b * 384 + 256) << 12) + (nt << 7) + n0;
    const _Float16* MhB = Mh + (size_t)(b * 4 + ct) * 4 * 8 * 512;

    for (int kt = 0; kt < 4; ++kt) {
#pragma unroll
        for (int s = 0; s < 2; ++s) {
            const int frag = wave + (s << 2);
            gl_lds16(MhB + ((size_t)kt * 8 + frag) * 512 + lane * 8, &sA[frag * 512]);
        }
        const float* cs = Cs + (size_t)(kt * 32 + k0) * NPIX;
        float ld[4][4];
        *(float4*)&ld[0][0] = *(const float4*)(cs);
        *(float4*)&ld[1][0] = *(const float4*)(cs + NPIX);
        *(float4*)&ld[2][0] = *(const float4*)(cs + 2 * NPIX);
        *(float4*)&ld[3][0] = *(const float4*)(cs + 3 * NPIX);
#pragma unroll
        for (int c = 0; c < 4; ++c) {
            const int n    = n0 + c;
            const int blkh = ((k0 >> 2) ^ (((n >> 4) & 3) << 1)) << 2;
            union { _Float16 h[4]; float2 f; } u;
            u.h[0] = (_Float16)ld[0][c];
            u.h[1] = (_Float16)ld[1][c];
            u.h[2] = (_Float16)ld[2][c];
            u.h[3] = (_Float16)ld[3][c];
            *(float2*)&sB[n * 40 + blkh] = u.f;
        }
        __syncthreads();

        half8 av[4], bv[4];
#pragma unroll
        for (int i = 0; i < 4; ++i)
            av[i] = *(const half8*)&sA[(((wm << 2) + i) << 9) + (lane << 3)];
#pragma unroll
        for (int j = 0; j < 4; ++j) {
            const int nj = (wn << 6) + (j << 4) + (lane & 15);
            const int qs = ((lane >> 4) ^ ((nj >> 4) & 3)) << 3;
            bv[j] = *(const half8*)&sB[nj * 40 + qs];
        }
#pragma unroll
        for (int i = 0; i < 4; ++i)
#pragma unroll
            for (int j = 0; j < 4; ++j)
                acc[i][j] = __builtin_amdgcn_mfma_f32_16x16x32_f16(av[i], bv[j], acc[i][j], 0, 0, 0);
        __syncthreads();
    }

    float* ob = out + (((size_t)b << 9) << 12);
#pragma unroll
    for (int i = 0; i < 4; ++i) {
        const int rc = (ct << 7) + (wm << 6) + (i << 4) + ((lane >> 4) << 2);
#pragma unroll
        for (int r = 0; r < 4; ++r) {
            const int c   = rc + r;
            const float s = gamma[c] * rsqrtf(var[c] + 1e-5f);
            const float t = fmaf(-mean[c], s, beta[c]);
            float* row = ob + ((size_t)c << 12) + (nt << 7);
#pragma unroll
            for (int j = 0; j < 4; ++j) {
                const int col = (wn << 6) + (j << 4) + (lane & 15);
                row[col] = fmaf(acc[i][j][r], s, t);
            }
        }
    }
}

// -------------------------------------------------------------------------
extern "C" void kernel_launch(void* const* d_in, const int* in_sizes, int n_in,
                              void* d_out, int out_size, void* d_ws, size_t ws_size,
                              hipStream_t stream)
{
    const float* x     = (const float*)d_in[0];
    const float* wA    = (const float*)d_in[1];
    const float* wB    = (const float*)d_in[2];
    const float* wC    = (const float*)d_in[3];
    const float* wProj = (const float*)d_in[4];
    const float* gamma = (const float*)d_in[5];
    const float* beta  = (const float*)d_in[6];
    const float* mean  = (const float*)d_in[7];
    const float* var   = (const float*)d_in[8];
    float* out = (float*)d_out;

    char* ws = (char*)d_ws;
    float*     P  = (float*)(ws);                       // 100663296 B
    float*     Gp = (float*)(ws + 100663296);           //  16777216 B
    float*     G  = (float*)(ws + 117440512);           //   1048576 B
    float*     M  = (float*)(ws + 118489088);           //   4194304 B
    _Float16*  Wh = (_Float16*)(ws + 122683392);        //    393216 B
    _Float16*  Mh = (_Float16*)(ws + 123076608);        //   2097152 B
    // total ws use: 125173760 bytes

    prep_w     <<<dim3(96),        256, 0, stream>>>(wA, wB, wC, Wh);
    conv_mfma  <<<dim3(32, 3, 16), 256, 0, stream>>>(x, Wh, P);
    softmax_rows<<<dim3(4096),     256, 0, stream>>>(P);
    g_partial  <<<dim3(16, 16),    256, 0, stream>>>(P, Gp);
    g_reduce   <<<dim3(256),       256, 0, stream>>>(Gp, G);
    proj_g     <<<dim3(16, 16),    256, 0, stream>>>(G, wProj, M);
    m_to_h     <<<dim3(512),       256, 0, stream>>>(M, Mh);
    final_mfma <<<dim3(32, 4, 16), 256, 0, stream>>>(P, Mh, gamma, beta, mean, var, out);
}

// Round 4
// 324.224 us; speedup vs baseline: 2.1063x; 1.1908x over previous
//
#include <hip/hip_runtime.h>
#include <cstddef>

#define NPIX 4096
#define CDIM 512

typedef _Float16 half8  __attribute__((ext_vector_type(8)));
typedef _Float16 half4v __attribute__((ext_vector_type(4)));
typedef float    f32x4  __attribute__((ext_vector_type(4)));

__device__ __forceinline__ void gl_lds16(const void* g, void* l) {
    __builtin_amdgcn_global_load_lds(
        (const __attribute__((address_space(1))) void*)g,
        (__attribute__((address_space(3))) void*)l, 16, 0, 0);
}

// -------------------------------------------------------------------------
// prep_w: wA/wB/wC fp32 [128][512] -> frag-blocked fp16 Wh (for conv A-op).
// -------------------------------------------------------------------------
__global__ __launch_bounds__(256)
void prep_w(const float* __restrict__ wA, const float* __restrict__ wB,
            const float* __restrict__ wC, _Float16* __restrict__ Wh)
{
    const int gid  = blockIdx.x * 256 + threadIdx.x;   // 0..24575
    const int lane = gid & 63;
    const int frag = gid >> 6;                         // 0..383
    const int msub = frag & 7, kt = (frag >> 3) & 15, mt = frag >> 7;
    const float* __restrict__ W = (mt == 0) ? wA : (mt == 1) ? wB : wC;
    const int m  = msub * 16 + (lane & 15);
    const int c0 = kt * 32 + ((lane >> 4) << 3);
    const float* src = W + m * CDIM + c0;
    union { _Float16 h[8]; float4 f; } u;
#pragma unroll
    for (int j = 0; j < 8; ++j) u.h[j] = (_Float16)src[j];
    *(float4*)(Wh + (size_t)frag * 512 + lane * 8) = u.f;
}

// -------------------------------------------------------------------------
// prep_wp: wProj fp32 [512][128] -> plain fp16 WpH [512][128] (h-contig).
// -------------------------------------------------------------------------
__global__ __launch_bounds__(256)
void prep_wp(const float* __restrict__ wProj, _Float16* __restrict__ WpH)
{
    const int gid = blockIdx.x * 256 + threadIdx.x;   // 0..8191
    const int i8  = gid * 8;
    float4 a = *(const float4*)(wProj + i8);
    float4 b = *(const float4*)(wProj + i8 + 4);
    union { _Float16 h[8]; float4 f; } u;
    u.h[0]=(_Float16)a.x; u.h[1]=(_Float16)a.y; u.h[2]=(_Float16)a.z; u.h[3]=(_Float16)a.w;
    u.h[4]=(_Float16)b.x; u.h[5]=(_Float16)b.y; u.h[6]=(_Float16)b.z; u.h[7]=(_Float16)b.w;
    *(float4*)(WpH + i8) = u.f;
}

// -------------------------------------------------------------------------
// conv_mfma: P[b, mt*128:+128, n] (fp16) = W_mt @ x[b]  via fp16 MFMA.
// -------------------------------------------------------------------------
__global__ __launch_bounds__(256)
void conv_mfma(const float* __restrict__ x, const _Float16* __restrict__ Wh,
               _Float16* __restrict__ P)
{
    const int nt = blockIdx.x, mt = blockIdx.y, b = blockIdx.z;
    const int tid  = threadIdx.x;
    const int wave = tid >> 6, lane = tid & 63;
    const int wm = wave >> 1, wn = wave & 1;

    __shared__ alignas(16) _Float16 sA[4096];        // 8 frag-blocks x 512
    __shared__ alignas(16) _Float16 sB[128 * 40];    // [n][32k + 8 pad], swizzled

    f32x4 acc[4][4];
#pragma unroll
    for (int i = 0; i < 4; ++i)
#pragma unroll
        for (int j = 0; j < 4; ++j)
#pragma unroll
            for (int e = 0; e < 4; ++e) acc[i][j][e] = 0.f;

    const int n0 = (tid & 31) << 2;
    const int k0 = (tid >> 5) << 2;
    const float* xb = x + ((size_t)b << 21) + (nt << 7) + n0;
    const _Float16* WhB = Wh + (size_t)mt * 128 * 512;

    for (int kt = 0; kt < 16; ++kt) {
#pragma unroll
        for (int s = 0; s < 2; ++s) {
            const int frag = wave + (s << 2);
            gl_lds16(WhB + ((size_t)kt * 8 + frag) * 512 + lane * 8, &sA[frag * 512]);
        }
        const float* xs = xb + (size_t)(kt * 32 + k0) * NPIX;
        float ld[4][4];
        *(float4*)&ld[0][0] = *(const float4*)(xs);
        *(float4*)&ld[1][0] = *(const float4*)(xs + NPIX);
        *(float4*)&ld[2][0] = *(const float4*)(xs + 2 * NPIX);
        *(float4*)&ld[3][0] = *(const float4*)(xs + 3 * NPIX);
#pragma unroll
        for (int c = 0; c < 4; ++c) {
            const int n    = n0 + c;
            const int blkh = ((k0 >> 2) ^ (((n >> 4) & 3) << 1)) << 2;
            union { _Float16 h[4]; float2 f; } u;
            u.h[0] = (_Float16)ld[0][c];
            u.h[1] = (_Float16)ld[1][c];
            u.h[2] = (_Float16)ld[2][c];
            u.h[3] = (_Float16)ld[3][c];
            *(float2*)&sB[n * 40 + blkh] = u.f;
        }
        __syncthreads();

        half8 av[4], bv[4];
#pragma unroll
        for (int i = 0; i < 4; ++i)
            av[i] = *(const half8*)&sA[(((wm << 2) + i) << 9) + (lane << 3)];
#pragma unroll
        for (int j = 0; j < 4; ++j) {
            const int nj = (wn << 6) + (j << 4) + (lane & 15);
            const int qs = ((lane >> 4) ^ ((nj >> 4) & 3)) << 3;
            bv[j] = *(const half8*)&sB[nj * 40 + qs];
        }
#pragma unroll
        for (int i = 0; i < 4; ++i)
#pragma unroll
            for (int j = 0; j < 4; ++j)
                acc[i][j] = __builtin_amdgcn_mfma_f32_16x16x32_f16(av[i], bv[j], acc[i][j], 0, 0, 0);
        __syncthreads();
    }

    _Float16* Pb = P + (((size_t)b * 384 + mt * 128) << 12) + (nt << 7);
#pragma unroll
    for (int i = 0; i < 4; ++i) {
        const int row0 = (wm << 6) + (i << 4) + ((lane >> 4) << 2);
#pragma unroll
        for (int j = 0; j < 4; ++j) {
            const int col = (wn << 6) + (j << 4) + (lane & 15);
#pragma unroll
            for (int r = 0; r < 4; ++r)
                Pb[(size_t)(row0 + r) * NPIX + col] = (_Float16)acc[i][j][r];
        }
    }
}

// -------------------------------------------------------------------------
// softmax_rows: fp16 in/out, fp32 math. Rows 0..127 (A) and 256..383 (Cs).
// -------------------------------------------------------------------------
__global__ __launch_bounds__(256)
void softmax_rows(_Float16* __restrict__ P)
{
    const int blk = blockIdx.x;            // 0..4095
    const int b   = blk >> 8;
    const int r   = blk & 255;
    const int m   = (r < 128) ? r : (r + 128);
    _Float16* row = P + (((size_t)b * 384 + m) << 12);
    const int tid = threadIdx.x;

    half8 h[2];
    float v[16];
    h[0] = *(const half8*)(row + tid * 16);
    h[1] = *(const half8*)(row + tid * 16 + 8);
    float mx = -3.402823466e38f;
#pragma unroll
    for (int j = 0; j < 16; ++j) { v[j] = (float)h[j >> 3][j & 7]; mx = fmaxf(mx, v[j]); }
#pragma unroll
    for (int o = 32; o > 0; o >>= 1) mx = fmaxf(mx, __shfl_xor(mx, o));
    __shared__ float redm[4];
    __shared__ float reds[4];
    const int wid = tid >> 6, lane = tid & 63;
    if (lane == 0) redm[wid] = mx;
    __syncthreads();
    mx = fmaxf(fmaxf(redm[0], redm[1]), fmaxf(redm[2], redm[3]));

    float s = 0.f;
#pragma unroll
    for (int j = 0; j < 16; ++j) { v[j] = __expf(v[j] - mx); s += v[j]; }
#pragma unroll
    for (int o = 32; o > 0; o >>= 1) s += __shfl_xor(s, o);
    if (lane == 0) reds[wid] = s;
    __syncthreads();
    s = (reds[0] + reds[1]) + (reds[2] + reds[3]);
    const float inv = 1.f / s;
#pragma unroll
    for (int j = 0; j < 16; ++j) h[j >> 3][j & 7] = (_Float16)(v[j] * inv);
    *(half8*)(row + tid * 16)     = h[0];
    *(half8*)(row + tid * 16 + 8) = h[1];
}

// -------------------------------------------------------------------------
// g_partial_mfma: Gp[b][kc][g][h] = A[g, chunk] . Bf[h, chunk]  (= G^T partial)
// Both operands n(k)-contiguous in P -> direct global half8 frags, no LDS.
// -------------------------------------------------------------------------
__global__ __launch_bounds__(256)
void g_partial_mfma(const _Float16* __restrict__ P, float* __restrict__ Gp)
{
    const int kc = blockIdx.x, b = blockIdx.y;
    const int tid  = threadIdx.x;
    const int wave = tid >> 6, lane = tid & 63;
    const int wm = wave >> 1, wn = wave & 1;

    const _Float16* Pa = P + ((size_t)b * 384 << 12);        // softmaxed A rows
    const _Float16* Pf = Pa + ((size_t)128 << 12);           // Bf rows

    f32x4 acc[4][4];
#pragma unroll
    for (int i = 0; i < 4; ++i)
#pragma unroll
        for (int j = 0; j < 4; ++j)
#pragma unroll
            for (int e = 0; e < 4; ++e) acc[i][j][e] = 0.f;

    const int klane = ((lane >> 4) << 3);
    const int rlane = lane & 15;
#pragma unroll 2
    for (int kt = 0; kt < 8; ++kt) {
        const int k = (kc << 8) + (kt << 5) + klane;
        half8 av[4], bv[4];
#pragma unroll
        for (int i = 0; i < 4; ++i)
            av[i] = *(const half8*)(Pa + ((size_t)((wm << 6) + (i << 4) + rlane) << 12) + k);
#pragma unroll
        for (int j = 0; j < 4; ++j)
            bv[j] = *(const half8*)(Pf + ((size_t)((wn << 6) + (j << 4) + rlane) << 12) + k);
#pragma unroll
        for (int i = 0; i < 4; ++i)
#pragma unroll
            for (int j = 0; j < 4; ++j)
                acc[i][j] = __builtin_amdgcn_mfma_f32_16x16x32_f16(av[i], bv[j], acc[i][j], 0, 0, 0);
    }

    float* O = Gp + (((size_t)b * 16 + kc) << 14);
#pragma unroll
    for (int i = 0; i < 4; ++i) {
        const int row0 = (wm << 6) + (i << 4) + ((lane >> 4) << 2);
#pragma unroll
        for (int j = 0; j < 4; ++j) {
            const int col = (wn << 6) + (j << 4) + rlane;
#pragma unroll
            for (int r = 0; r < 4; ++r)
                O[(size_t)(row0 + r) * 128 + col] = acc[i][j][r];
        }
    }
}

// -------------------------------------------------------------------------
// g_reduce_cvt: Gt[b][g][h] (fp16, = G^T) = sum of 16 fp32 partials.
// -------------------------------------------------------------------------
__global__ __launch_bounds__(256)
void g_reduce_cvt(const float* __restrict__ Gp, _Float16* __restrict__ Gt)
{
    const int gid  = blockIdx.x * 256 + threadIdx.x;  // 0..32767
    const int i8   = gid * 8;
    const int b    = i8 >> 14;
    const int rr   = i8 & 16383;
    const float* base = Gp + ((size_t)b << 18) + rr;
    float s[8];
#pragma unroll
    for (int e = 0; e < 8; ++e) s[e] = 0.f;
#pragma unroll
    for (int kc = 0; kc < 16; ++kc) {
        float4 v0 = *(const float4*)(base + ((size_t)kc << 14));
        float4 v1 = *(const float4*)(base + ((size_t)kc << 14) + 4);
        s[0]+=v0.x; s[1]+=v0.y; s[2]+=v0.z; s[3]+=v0.w;
        s[4]+=v1.x; s[5]+=v1.y; s[6]+=v1.z; s[7]+=v1.w;
    }
    union { _Float16 h[8]; float4 f; } u;
#pragma unroll
    for (int e = 0; e < 8; ++e) u.h[e] = (_Float16)s[e];
    *(float4*)(Gt + ((size_t)b << 14) + rr) = u.f;
}

// -------------------------------------------------------------------------
// proj_mfma: Mh[b][c][g] = sum_h WpH[c][h] * Gt[g][h].  Direct global frags.
// -------------------------------------------------------------------------
__global__ __launch_bounds__(256)
void proj_mfma(const _Float16* __restrict__ WpH, const _Float16* __restrict__ Gt,
               _Float16* __restrict__ Mh)
{
    const int ct = blockIdx.x, b = blockIdx.y;
    const int tid  = threadIdx.x;
    const int wave = tid >> 6, lane = tid & 63;
    const int wm = wave >> 1, wn = wave & 1;

    f32x4 acc[4][4];
#pragma unroll
    for (int i = 0; i < 4; ++i)
#pragma unroll
        for (int j = 0; j < 4; ++j)
#pragma unroll
            for (int e = 0; e < 4; ++e) acc[i][j][e] = 0.f;

    const int klane = ((lane >> 4) << 3);
    const int rlane = lane & 15;
    const _Float16* Gb = Gt + ((size_t)b << 14);
#pragma unroll
    for (int kt = 0; kt < 4; ++kt) {
        const int k = (kt << 5) + klane;
        half8 av[4], bv[4];
#pragma unroll
        for (int i = 0; i < 4; ++i)
            av[i] = *(const half8*)(WpH + (size_t)((ct << 7) + (wm << 6) + (i << 4) + rlane) * 128 + k);
#pragma unroll
        for (int j = 0; j < 4; ++j)
            bv[j] = *(const half8*)(Gb + (size_t)((wn << 6) + (j << 4) + rlane) * 128 + k);
#pragma unroll
        for (int i = 0; i < 4; ++i)
#pragma unroll
            for (int j = 0; j < 4; ++j)
                acc[i][j] = __builtin_amdgcn_mfma_f32_16x16x32_f16(av[i], bv[j], acc[i][j], 0, 0, 0);
    }

    _Float16* Mb = Mh + ((size_t)b << 16);
#pragma unroll
    for (int i = 0; i < 4; ++i) {
        const int row0 = (ct << 7) + (wm << 6) + (i << 4) + ((lane >> 4) << 2);
#pragma unroll
        for (int j = 0; j < 4; ++j) {
            const int col = (wn << 6) + (j << 4) + rlane;
#pragma unroll
            for (int r = 0; r < 4; ++r)
                Mb[(size_t)(row0 + r) * 128 + col] = (_Float16)acc[i][j][r];
        }
    }
}

// -------------------------------------------------------------------------
// final_mfma: out = BN(Mh[b] @ Cs[b]).  A direct global frags from Mh;
// B = fp16 Cs rows of P, register 4x4 transpose -> swizzled LDS.
// -------------------------------------------------------------------------
__global__ __launch_bounds__(256)
void final_mfma(const _Float16* __restrict__ P, const _Float16* __restrict__ Mh,
                const float* __restrict__ gamma, const float* __restrict__ beta,
                const float* __restrict__ mean,  const float* __restrict__ var,
                float* __restrict__ out)
{
    const int nt = blockIdx.x, ct = blockIdx.y, b = blockIdx.z;
    const int tid  = threadIdx.x;
    const int wave = tid >> 6, lane = tid & 63;
    const int wm = wave >> 1, wn = wave & 1;

    __shared__ alignas(16) _Float16 sB[128 * 40];

    f32x4 acc[4][4];
#pragma unroll
    for (int i = 0; i < 4; ++i)
#pragma unroll
        for (int j = 0; j < 4; ++j)
#pragma unroll
            for (int e = 0; e < 4; ++e) acc[i][j][e] = 0.f;

    const int n0 = (tid & 31) << 2;
    const int k0 = (tid >> 5) << 2;
    const int klane = ((lane >> 4) << 3);
    const int rlane = lane & 15;
    const _Float16* Cs  = P + (((size_t)b * 384 + 256) << 12) + (nt << 7) + n0;
    const _Float16* MhB = Mh + ((size_t)b << 16) + ((size_t)(ct << 7) << 7);

    for (int kt = 0; kt < 4; ++kt) {
        const _Float16* cs = Cs + ((size_t)((kt << 5) + k0) << 12);
        half4v ld0 = *(const half4v*)(cs);
        half4v ld1 = *(const half4v*)(cs + NPIX);
        half4v ld2 = *(const half4v*)(cs + 2 * NPIX);
        half4v ld3 = *(const half4v*)(cs + 3 * NPIX);
#pragma unroll
        for (int c = 0; c < 4; ++c) {
            const int n    = n0 + c;
            const int blkh = ((k0 >> 2) ^ (((n >> 4) & 3) << 1)) << 2;
            half4v col = { ld0[c], ld1[c], ld2[c], ld3[c] };
            *(half4v*)&sB[n * 40 + blkh] = col;
        }
        __syncthreads();

        half8 av[4], bv[4];
#pragma unroll
        for (int i = 0; i < 4; ++i)
            av[i] = *(const half8*)(MhB + (size_t)((wm << 6) + (i << 4) + rlane) * 128 + (kt << 5) + klane);
#pragma unroll
        for (int j = 0; j < 4; ++j) {
            const int nj = (wn << 6) + (j << 4) + rlane;
            const int qs = ((lane >> 4) ^ ((nj >> 4) & 3)) << 3;
            bv[j] = *(const half8*)&sB[nj * 40 + qs];
        }
#pragma unroll
        for (int i = 0; i < 4; ++i)
#pragma unroll
            for (int j = 0; j < 4; ++j)
                acc[i][j] = __builtin_amdgcn_mfma_f32_16x16x32_f16(av[i], bv[j], acc[i][j], 0, 0, 0);
        __syncthreads();
    }

    float* ob = out + (((size_t)b << 9) << 12);
#pragma unroll
    for (int i = 0; i < 4; ++i) {
        const int rc = (ct << 7) + (wm << 6) + (i << 4) + ((lane >> 4) << 2);
#pragma unroll
        for (int r = 0; r < 4; ++r) {
            const int c   = rc + r;
            const float s = gamma[c] * rsqrtf(var[c] + 1e-5f);
            const float t = fmaf(-mean[c], s, beta[c]);
            float* row = ob + ((size_t)c << 12) + (nt << 7);
#pragma unroll
            for (int j = 0; j < 4; ++j) {
                const int col = (wn << 6) + (j << 4) + rlane;
                row[col] = fmaf(acc[i][j][r], s, t);
            }
        }
    }
}

// -------------------------------------------------------------------------
extern "C" void kernel_launch(void* const* d_in, const int* in_sizes, int n_in,
                              void* d_out, int out_size, void* d_ws, size_t ws_size,
                              hipStream_t stream)
{
    const float* x     = (const float*)d_in[0];
    const float* wA    = (const float*)d_in[1];
    const float* wB    = (const float*)d_in[2];
    const float* wC    = (const float*)d_in[3];
    const float* wProj = (const float*)d_in[4];
    const float* gamma = (const float*)d_in[5];
    const float* beta  = (const float*)d_in[6];
    const float* mean  = (const float*)d_in[7];
    const float* var   = (const float*)d_in[8];
    float* out = (float*)d_out;

    char* ws = (char*)d_ws;
    _Float16* P   = (_Float16*)(ws);                   // 16*384*4096*2 = 50331648
    float*    Gp  = (float*)(ws + 50331648);           // 16*16*16384*4 = 16777216
    _Float16* Gt  = (_Float16*)(ws + 67108864);        // 16*16384*2    =   524288
    _Float16* WpH = (_Float16*)(ws + 67633152);        // 512*128*2     =   131072
    _Float16* Mh  = (_Float16*)(ws + 67764224);        // 16*512*128*2  =  2097152
    _Float16* Wh  = (_Float16*)(ws + 69861376);        // 384*512*2     =   393216
    // total ws use: 70254592 bytes

    prep_w        <<<dim3(96),        256, 0, stream>>>(wA, wB, wC, Wh);
    prep_wp       <<<dim3(32),        256, 0, stream>>>(wProj, WpH);
    conv_mfma     <<<dim3(32, 3, 16), 256, 0, stream>>>(x, Wh, P);
    softmax_rows  <<<dim3(4096),      256, 0, stream>>>(P);
    g_partial_mfma<<<dim3(16, 16),    256, 0, stream>>>(P, Gp);
    g_reduce_cvt  <<<dim3(128),       256, 0, stream>>>(Gp, Gt);
    proj_mfma     <<<dim3(4, 16),     256, 0, stream>>>(WpH, Gt, Mh);
    final_mfma    <<<dim3(32, 4, 16), 256, 0, stream>>>(P, Mh, gamma, beta, mean, var, out);
}